// Round 3
// baseline (740.512 us; speedup 1.0000x reference)
//
#include <hip/hip_runtime.h>
#include <hip/hip_bf16.h>
#include <math.h>

#define T_TOK 8192
#define E_EXP 8
#define D_DIM 1024
#define H_DIM 4096
#define K_CAP 1024

typedef __attribute__((ext_vector_type(8))) short short8;
typedef __attribute__((ext_vector_type(4))) float floatx4;

typedef __attribute__((address_space(3))) unsigned int lds_u32_t;
typedef __attribute__((address_space(1))) unsigned int gbl_u32_t;
#define ASYNC_CP16(gptr, lptr) \
  __builtin_amdgcn_global_load_lds((gbl_u32_t*)(gptr), (lds_u32_t*)(lptr), 16, 0, 0)

static __device__ __forceinline__ unsigned int f2bf_u(float f) {
  union { float f; unsigned int u; } v; v.f = f;
  unsigned int r = v.u + 0x7FFF + ((v.u >> 16) & 1);
  return r >> 16;
}

// ---------------- zero output ----------------
__global__ __launch_bounds__(256) void zero_kernel(float* __restrict__ p, int n4) {
  int i = blockIdx.x * 256 + threadIdx.x;
  if (i < n4) ((floatx4*)p)[i] = (floatx4)0.0f;
}

// ---------------- fp32 -> bf16 convert (x) ----------------
__global__ __launch_bounds__(256)
void convert_kernel(const float* __restrict__ x, unsigned short* __restrict__ xb, int n4) {
  int i = blockIdx.x * 256 + threadIdx.x;
  if (i < n4) {
    float4 v = ((const float4*)x)[i];
    uint2 u;
    u.x = f2bf_u(v.x) | (f2bf_u(v.y) << 16);
    u.y = f2bf_u(v.z) | (f2bf_u(v.w) << 16);
    ((uint2*)xb)[i] = u;
  }
}

// ---------------- transpose + convert: W [E][KD][ND] f32 -> WT [E][ND][KD] bf16 ----
// 64x64 tiles, 16B/lane both sides.
template <int KD, int ND>
__global__ __launch_bounds__(256)
void transpose_kernel(const float* __restrict__ w, unsigned short* __restrict__ wt) {
  int e = blockIdx.z;
  int n0 = blockIdx.x * 64, k0 = blockIdx.y * 64;
  __shared__ float ts[64][65];
  int tid = threadIdx.x;
  int rr = tid >> 4;          // 0..15
  int cc = (tid & 15) * 4;    // 0..60
  const float* src = w + ((size_t)e * KD + k0 + rr) * ND + n0 + cc;
#pragma unroll
  for (int it = 0; it < 4; it++) {
    float4 v = *(const float4*)(src + (size_t)it * 16 * ND);
    int r = rr + it * 16;
    ts[r][cc + 0] = v.x; ts[r][cc + 1] = v.y; ts[r][cc + 2] = v.z; ts[r][cc + 3] = v.w;
  }
  __syncthreads();
  int n = tid >> 3;           // 0..31
  int k8 = (tid & 7) * 8;     // 0..56
#pragma unroll
  for (int it = 0; it < 2; it++) {
    int nn = n + it * 32;
    unsigned int u[4];
#pragma unroll
    for (int j = 0; j < 4; j++)
      u[j] = f2bf_u(ts[k8 + 2 * j][nn]) | (f2bf_u(ts[k8 + 2 * j + 1][nn]) << 16);
    *(uint4*)&wt[((size_t)e * ND + n0 + nn) * KD + k0 + k8] = *(uint4*)u;
  }
}

// ---------------- router: fp64 logits + softmax, build sort keys ----------------
__global__ __launch_bounds__(256)
void router_kernel(const float* __restrict__ x, const float* __restrict__ rw,
                   float* __restrict__ logits_out, float* __restrict__ probs_ws,
                   unsigned long long* __restrict__ keys_ws) {
  int t = blockIdx.x;
  int tid = threadIdx.x;
  int lane = tid & 63, wid = tid >> 6;
  __shared__ float xs[D_DIM];
  __shared__ double dred[4 * E_EXP];
  __shared__ double dlog[E_EXP];
  for (int i = tid; i < D_DIM; i += 256) xs[i] = x[(size_t)t * D_DIM + i];
  __syncthreads();
#pragma unroll
  for (int e = 0; e < E_EXP; e++) {
    double s = 0.0;
#pragma unroll
    for (int i = 0; i < 4; i++) {
      int d = tid + i * 256;
      s += (double)xs[d] * (double)rw[e * D_DIM + d];
    }
#pragma unroll
    for (int off = 32; off > 0; off >>= 1) s += __shfl_down(s, off, 64);
    if (lane == 0) dred[wid * E_EXP + e] = s;
  }
  __syncthreads();
  if (tid < E_EXP) {
    double s = dred[tid] + dred[E_EXP + tid] + dred[2 * E_EXP + tid] + dred[3 * E_EXP + tid];
    dlog[tid] = s;
    logits_out[(size_t)t * E_EXP + tid] = (float)s;
  }
  __syncthreads();
  if (tid == 0) {
    double m = dlog[0];
#pragma unroll
    for (int e = 1; e < E_EXP; e++) m = dlog[e] > m ? dlog[e] : m;
    double ex[E_EXP], Z = 0.0;
#pragma unroll
    for (int e = 0; e < E_EXP; e++) { ex[e] = exp(dlog[e] - m); Z += ex[e]; }
#pragma unroll
    for (int e = 0; e < E_EXP; e++) {
      double p = ex[e] / Z;
      probs_ws[e * T_TOK + t] = (float)p;
      unsigned long long b = (unsigned long long)__double_as_longlong(p);
      keys_ws[e * T_TOK + t] = (b & ~8191ULL) | (unsigned long long)(8191 - t);
    }
  }
}

// ---------------- exact top-k by rank counting (256 blocks) ----------------
__global__ __launch_bounds__(256)
void topk_kernel(const unsigned long long* __restrict__ keys_ws,
                 const float* __restrict__ probs_ws,
                 int* __restrict__ sel_ws, float* __restrict__ wt_ws,
                 float* __restrict__ selout) {
  int e = blockIdx.x >> 5, seg = blockIdx.x & 31;
  int tid = threadIdx.x;
  const unsigned long long* keys = keys_ws + (size_t)e * T_TOK;
  __shared__ unsigned long long kbuf[2048];
  int t = seg * 256 + tid;
  unsigned long long own = keys[t];
  int rank = 0;
  for (int pass = 0; pass < 4; pass++) {
    __syncthreads();
    for (int j = tid; j < 2048; j += 256) kbuf[j] = keys[pass * 2048 + j];
    __syncthreads();
#pragma unroll 8
    for (int j = 0; j < 2048; j++) rank += (kbuf[j] > own);
  }
  if (rank < K_CAP) {
    sel_ws[e * K_CAP + rank] = t;
    wt_ws[e * K_CAP + rank] = probs_ws[e * T_TOK + t];
    selout[e * K_CAP + rank] = (float)t;
  }
}

// ---------------- m97-style bf16 MFMA GEMM, expert-per-XCD + split-K ----------------
// grid = dim3(E, NT*MT*SPLIT). bid%8 == e -> one expert per XCD (L2 locality).
template <int MODE, int KDIM, int NDIM, int SPLIT, int NT>
__global__ __launch_bounds__(256)
void gemm_kernel(const unsigned short* __restrict__ abase,
                 const unsigned short* __restrict__ bt,
                 const float* __restrict__ bias,
                 const int* __restrict__ sel,
                 const float* __restrict__ wt,
                 unsigned short* __restrict__ hout,
                 float* __restrict__ results) {
  int e = blockIdx.x;
  int rest = blockIdx.y;
  int s = rest & (SPLIT - 1);
  int nt = (rest / SPLIT) % NT;
  int mt = rest / (SPLIT * NT);
  int n0 = nt * 128;
  int m0 = mt * 128;
  const int KCH = KDIM / SPLIT;
  int kbase = s * KCH;

  int tid = threadIdx.x;
  int lane = tid & 63, wid = tid >> 6;
  int wave_m = wid >> 1, wave_n = wid & 1;
  __shared__ unsigned short As[128 * 32];
  __shared__ unsigned short Bs[128 * 32];

  int r0 = tid >> 2;            // 0..63
  int coff = (tid & 3) * 8;     // shorts within 32-short slice
  const unsigned short* aptr0;
  const unsigned short* aptr1;
  if (MODE == 1) {
    aptr0 = abase + (size_t)sel[e * K_CAP + m0 + r0] * KDIM + kbase + coff;
    aptr1 = abase + (size_t)sel[e * K_CAP + m0 + 64 + r0] * KDIM + kbase + coff;
  } else {
    aptr0 = abase + ((size_t)e * K_CAP + m0 + r0) * KDIM + kbase + coff;
    aptr1 = aptr0 + (size_t)64 * KDIM;
  }
  const unsigned short* bptr0 = bt + ((size_t)e * NDIM + n0 + r0) * KDIM + kbase + coff;
  const unsigned short* bptr1 = bptr0 + (size_t)64 * KDIM;

  char* ldsA0 = (char*)As + wid * 1024;
  char* ldsA1 = ldsA0 + 4096;
  char* ldsB0 = (char*)Bs + wid * 1024;
  char* ldsB1 = ldsB0 + 4096;

  floatx4 acc[4][4];
#pragma unroll
  for (int i = 0; i < 4; i++)
#pragma unroll
    for (int j = 0; j < 4; j++) acc[i][j] = (floatx4)0.0f;

  int lm = lane & 15;
  int q8 = (lane >> 4) * 8;

  for (int k0 = 0; k0 < KCH; k0 += 32) {
    ASYNC_CP16(aptr0, ldsA0);
    ASYNC_CP16(aptr1, ldsA1);
    ASYNC_CP16(bptr0, ldsB0);
    ASYNC_CP16(bptr1, ldsB1);
    aptr0 += 32; aptr1 += 32; bptr0 += 32; bptr1 += 32;
    __syncthreads();
    short8 av[4], bv[4];
#pragma unroll
    for (int i = 0; i < 4; i++) {
      av[i] = *(const short8*)&As[(wave_m * 64 + i * 16 + lm) * 32 + q8];
      bv[i] = *(const short8*)&Bs[(wave_n * 64 + i * 16 + lm) * 32 + q8];
    }
#pragma unroll
    for (int mi = 0; mi < 4; mi++)
#pragma unroll
      for (int ni = 0; ni < 4; ni++)
        acc[mi][ni] = __builtin_amdgcn_mfma_f32_16x16x32_bf16(av[mi], bv[ni], acc[mi][ni], 0, 0, 0);
    __syncthreads();
  }

  // ---- epilogue ----
  int quad = lane >> 4;
  float bs[4];
#pragma unroll
  for (int ni = 0; ni < 4; ni++)
    bs[ni] = (MODE == 1 || s == 0) ? bias[e * NDIM + n0 + wave_n * 64 + ni * 16 + lm] : 0.0f;
#pragma unroll
  for (int mi = 0; mi < 4; mi++) {
#pragma unroll
    for (int rg = 0; rg < 4; rg++) {
      int m_l = wave_m * 64 + mi * 16 + quad * 4 + rg;
      int m_g = m0 + m_l;
      if (MODE == 1) {
#pragma unroll
        for (int ni = 0; ni < 4; ni++) {
          int n_l = wave_n * 64 + ni * 16 + lm;
          float v = acc[mi][ni][rg] + bs[ni];
          float gl = 0.5f * v * (1.0f + erff(v * 0.70710678118f));  // exact GELU
          hout[((size_t)e * K_CAP + m_g) * H_DIM + n0 + n_l] = (unsigned short)f2bf_u(gl);
        }
      } else {
        int tok = sel[e * K_CAP + m_g];
        float wgt = wt[e * K_CAP + m_g];
#pragma unroll
        for (int ni = 0; ni < 4; ni++) {
          int n_l = wave_n * 64 + ni * 16 + lm;
          float v = (acc[mi][ni][rg] + bs[ni]) * wgt;
          atomicAdd(&results[(size_t)tok * D_DIM + n0 + n_l], v);
        }
      }
    }
  }
}

extern "C" void kernel_launch(void* const* d_in, const int* in_sizes, int n_in,
                              void* d_out, int out_size, void* d_ws, size_t ws_size,
                              hipStream_t stream) {
  const float* x  = (const float*)d_in[0];
  const float* rw = (const float*)d_in[1];
  const float* w1 = (const float*)d_in[2];
  const float* b1 = (const float*)d_in[3];
  const float* w2 = (const float*)d_in[4];
  const float* b2 = (const float*)d_in[5];

  float* out_res = (float*)d_out;                      // [8192][1024] fp32
  float* out_log = out_res + (size_t)T_TOK * D_DIM;    // [8192][8] fp32
  float* out_sel = out_log + (size_t)T_TOK * E_EXP;    // [8][1024] token ids as float

  char* ws = (char*)d_ws;
  float* probs_ws = (float*)ws;                                      // 256KB
  unsigned long long* keys_ws = (unsigned long long*)(ws + 262144);  // 512KB
  int* sel_ws = (int*)(ws + 786432);                                 // 32KB
  float* wt_ws = (float*)(ws + 819200);                              // 32KB
  unsigned short* x_bf = (unsigned short*)(ws + 1048576);            // 16MB
  unsigned short* h_ws = (unsigned short*)(ws + 17825792);           // 64MB
  unsigned short* t_buf = (unsigned short*)(ws + 84934656);          // 64MB (w1t, then w2t)

  zero_kernel<<<(T_TOK * D_DIM / 4 + 255) / 256, 256, 0, stream>>>(out_res, T_TOK * D_DIM / 4);

  convert_kernel<<<(T_TOK * D_DIM / 4 + 255) / 256, 256, 0, stream>>>(
      x, x_bf, T_TOK * D_DIM / 4);

  router_kernel<<<T_TOK, 256, 0, stream>>>(x, rw, out_log, probs_ws, keys_ws);

  topk_kernel<<<256, 256, 0, stream>>>(keys_ws, probs_ws, sel_ws, wt_ws, out_sel);

  // w1 [E][D][H] -> w1t [E][H][D] bf16
  transpose_kernel<D_DIM, H_DIM><<<dim3(H_DIM / 64, D_DIM / 64, E_EXP), 256, 0, stream>>>(
      w1, t_buf);

  // H = gelu(Xg @ W1 + b1) -> bf16   (grid.x = expert -> XCD affinity)
  gemm_kernel<1, D_DIM, H_DIM, 1, H_DIM / 128>
      <<<dim3(E_EXP, (H_DIM / 128) * (K_CAP / 128)), 256, 0, stream>>>(
      x_bf, t_buf, b1, sel_ws, wt_ws, h_ws, nullptr);

  // w2 [E][H][D] -> w2t [E][D][H] bf16 (reuse t_buf)
  transpose_kernel<H_DIM, D_DIM><<<dim3(D_DIM / 64, H_DIM / 64, E_EXP), 256, 0, stream>>>(
      w2, t_buf);

  // results += weight * (H @ W2 + b2), scattered by token; split-K=2
  gemm_kernel<2, H_DIM, D_DIM, 2, D_DIM / 128>
      <<<dim3(E_EXP, (D_DIM / 128) * (K_CAP / 128) * 2), 256, 0, stream>>>(
      h_ws, t_buf, b2, sel_ws, wt_ws, nullptr, out_res);
}

// Round 4
// 685.234 us; speedup vs baseline: 1.0807x; 1.0807x over previous
//
#include <hip/hip_runtime.h>
#include <hip/hip_bf16.h>
#include <math.h>

#define T_TOK 8192
#define E_EXP 8
#define D_DIM 1024
#define H_DIM 4096
#define K_CAP 1024

typedef __attribute__((ext_vector_type(8))) short short8;
typedef __attribute__((ext_vector_type(4))) float floatx4;
typedef __attribute__((ext_vector_type(16))) float floatx16;

typedef __attribute__((address_space(3))) unsigned int lds_u32_t;
typedef __attribute__((address_space(1))) unsigned int gbl_u32_t;
#define ASYNC_CP16(gptr, lptr) \
  __builtin_amdgcn_global_load_lds((gbl_u32_t*)(gptr), (lds_u32_t*)(lptr), 16, 0, 0)

static __device__ __forceinline__ unsigned int f2bf_u(float f) {
  union { float f; unsigned int u; } v; v.f = f;
  unsigned int r = v.u + 0x7FFF + ((v.u >> 16) & 1);
  return r >> 16;
}

// ---------------- zero output ----------------
__global__ __launch_bounds__(256) void zero_kernel(float* __restrict__ p, int n4) {
  int i = blockIdx.x * 256 + threadIdx.x;
  if (i < n4) ((floatx4*)p)[i] = (floatx4)0.0f;
}

// ---------------- transpose + convert: W [E][KD][ND] f32 -> WT [E][ND][KD] bf16 ----
template <int KD, int ND>
__global__ __launch_bounds__(256)
void transpose_kernel(const float* __restrict__ w, unsigned short* __restrict__ wt) {
  int e = blockIdx.z;
  int n0 = blockIdx.x * 64, k0 = blockIdx.y * 64;
  __shared__ float ts[64][65];
  int tid = threadIdx.x;
  int rr = tid >> 4;          // 0..15
  int cc = (tid & 15) * 4;    // 0..60
  const float* src = w + ((size_t)e * KD + k0 + rr) * ND + n0 + cc;
#pragma unroll
  for (int it = 0; it < 4; it++) {
    float4 v = *(const float4*)(src + (size_t)it * 16 * ND);
    int r = rr + it * 16;
    ts[r][cc + 0] = v.x; ts[r][cc + 1] = v.y; ts[r][cc + 2] = v.z; ts[r][cc + 3] = v.w;
  }
  __syncthreads();
  int n = tid >> 3;           // 0..31
  int k8 = (tid & 7) * 8;     // 0..56
#pragma unroll
  for (int it = 0; it < 2; it++) {
    int nn = n + it * 32;
    unsigned int u[4];
#pragma unroll
    for (int j = 0; j < 4; j++)
      u[j] = f2bf_u(ts[k8 + 2 * j][nn]) | (f2bf_u(ts[k8 + 2 * j + 1][nn]) << 16);
    *(uint4*)&wt[((size_t)e * ND + n0 + nn) * KD + k0 + k8] = *(uint4*)u;
  }
}

// ---------------- router: fp64 logits + softmax, keys; also emits x_bf ----------------
__global__ __launch_bounds__(256)
void router_kernel(const float* __restrict__ x, const float* __restrict__ rw,
                   float* __restrict__ logits_out, float* __restrict__ probs_ws,
                   unsigned long long* __restrict__ keys_ws,
                   unsigned short* __restrict__ x_bf) {
  int t = blockIdx.x;
  int tid = threadIdx.x;
  int lane = tid & 63, wid = tid >> 6;
  __shared__ float xs[D_DIM];
  __shared__ double dred[4 * E_EXP];
  __shared__ double dlog[E_EXP];
  for (int i = tid; i < D_DIM; i += 256) xs[i] = x[(size_t)t * D_DIM + i];
  __syncthreads();
  {  // fused x -> bf16 (replaces separate convert kernel)
    int i4 = tid * 4;
    uint2 u;
    u.x = f2bf_u(xs[i4 + 0]) | (f2bf_u(xs[i4 + 1]) << 16);
    u.y = f2bf_u(xs[i4 + 2]) | (f2bf_u(xs[i4 + 3]) << 16);
    ((uint2*)(x_bf + (size_t)t * D_DIM))[tid] = u;
  }
#pragma unroll
  for (int e = 0; e < E_EXP; e++) {
    double s = 0.0;
#pragma unroll
    for (int i = 0; i < 4; i++) {
      int d = tid + i * 256;
      s += (double)xs[d] * (double)rw[e * D_DIM + d];
    }
#pragma unroll
    for (int off = 32; off > 0; off >>= 1) s += __shfl_down(s, off, 64);
    if (lane == 0) dred[wid * E_EXP + e] = s;
  }
  __syncthreads();
  if (tid < E_EXP) {
    double s = dred[tid] + dred[E_EXP + tid] + dred[2 * E_EXP + tid] + dred[3 * E_EXP + tid];
    dlog[tid] = s;
    logits_out[(size_t)t * E_EXP + tid] = (float)s;
  }
  __syncthreads();
  if (tid == 0) {
    double m = dlog[0];
#pragma unroll
    for (int e = 1; e < E_EXP; e++) m = dlog[e] > m ? dlog[e] : m;
    double ex[E_EXP], Z = 0.0;
#pragma unroll
    for (int e = 0; e < E_EXP; e++) { ex[e] = exp(dlog[e] - m); Z += ex[e]; }
#pragma unroll
    for (int e = 0; e < E_EXP; e++) {
      double p = ex[e] / Z;
      probs_ws[e * T_TOK + t] = (float)p;
      unsigned long long b = (unsigned long long)__double_as_longlong(p);
      keys_ws[e * T_TOK + t] = (b & ~8191ULL) | (unsigned long long)(8191 - t);
    }
  }
}

// ---------------- exact top-k by rank counting (256 blocks) ----------------
__global__ __launch_bounds__(256)
void topk_kernel(const unsigned long long* __restrict__ keys_ws,
                 const float* __restrict__ probs_ws,
                 int* __restrict__ sel_ws, float* __restrict__ wt_ws,
                 float* __restrict__ selout) {
  int e = blockIdx.x >> 5, seg = blockIdx.x & 31;
  int tid = threadIdx.x;
  const unsigned long long* keys = keys_ws + (size_t)e * T_TOK;
  __shared__ unsigned long long kbuf[2048];
  int t = seg * 256 + tid;
  unsigned long long own = keys[t];
  int rank = 0;
  for (int pass = 0; pass < 4; pass++) {
    __syncthreads();
    for (int j = tid; j < 2048; j += 256) kbuf[j] = keys[pass * 2048 + j];
    __syncthreads();
#pragma unroll 8
    for (int j = 0; j < 2048; j++) rank += (kbuf[j] > own);
  }
  if (rank < K_CAP) {
    sel_ws[e * K_CAP + rank] = t;
    wt_ws[e * K_CAP + rank] = probs_ws[e * T_TOK + t];
    selout[e * K_CAP + rank] = (float)t;
  }
}

// ---------------- GEMM core: 128x128 tile, BK=64, 32x32x16 MFMA ----------------
// LDS layout: two half-planes [khalf][row][32 shorts] (64B rows, m97 bank pattern).
template <int MODE, int KDIM, int NDIM>
__device__ __forceinline__ void gemm_core(
    int e, int m0, int n0, int kbase, int kch, bool add_bias,
    const unsigned short* __restrict__ abase,
    const unsigned short* __restrict__ bt,
    const float* __restrict__ bias,
    const int* __restrict__ sel,
    const float* __restrict__ wt,
    unsigned short* __restrict__ hout,
    float* __restrict__ results) {
  __shared__ unsigned short As[128 * 64];  // 16 KB
  __shared__ unsigned short Bs[128 * 64];  // 16 KB
  int tid = threadIdx.x;
  int lane = tid & 63, w = tid >> 6;
  int wave_m = w >> 1, wave_n = w & 1;

  // staging: chunk c = {w, 4+w, 8+w, 12+w}; c<8 -> khalf0 rows (c&7)*16.., c>=8 khalf1
  int srow = lane >> 2;             // 0..15 row-within-group
  int scol = (lane & 3) * 8;        // shorts within 32-short half-row
  int rowA0 = w * 16 + srow;        // rows 0..63
  int rowA1 = (4 + w) * 16 + srow;  // rows 64..127
  const unsigned short *arow0, *arow1;
  if (MODE == 1) {
    arow0 = abase + (size_t)sel[e * K_CAP + m0 + rowA0] * KDIM + kbase + scol;
    arow1 = abase + (size_t)sel[e * K_CAP + m0 + rowA1] * KDIM + kbase + scol;
  } else {
    arow0 = abase + ((size_t)e * K_CAP + m0 + rowA0) * KDIM + kbase + scol;
    arow1 = abase + ((size_t)e * K_CAP + m0 + rowA1) * KDIM + kbase + scol;
  }
  const unsigned short* brow0 = bt + ((size_t)e * NDIM + n0 + rowA0) * KDIM + kbase + scol;
  const unsigned short* brow1 = bt + ((size_t)e * NDIM + n0 + rowA1) * KDIM + kbase + scol;

  char* lA0 = (char*)As + w * 1024;
  char* lA1 = (char*)As + (4 + w) * 1024;
  char* lA2 = (char*)As + (8 + w) * 1024;
  char* lA3 = (char*)As + (12 + w) * 1024;
  char* lB0 = (char*)Bs + w * 1024;
  char* lB1 = (char*)Bs + (4 + w) * 1024;
  char* lB2 = (char*)Bs + (8 + w) * 1024;
  char* lB3 = (char*)Bs + (12 + w) * 1024;

  floatx16 acc[2][2];
#pragma unroll
  for (int i = 0; i < 2; i++)
#pragma unroll
    for (int j = 0; j < 2; j++) acc[i][j] = (floatx16)0.0f;

  int am = lane & 31;          // row/col within 32-tile
  int k8 = (lane >> 5) * 8;    // shorts

  for (int k0 = 0; k0 < kch; k0 += 64) {
    ASYNC_CP16(arow0, lA0);          // khalf 0, rows 0..63
    ASYNC_CP16(arow1, lA1);          // khalf 0, rows 64..127
    ASYNC_CP16(arow0 + 32, lA2);     // khalf 1, rows 0..63
    ASYNC_CP16(arow1 + 32, lA3);     // khalf 1, rows 64..127
    ASYNC_CP16(brow0, lB0);
    ASYNC_CP16(brow1, lB1);
    ASYNC_CP16(brow0 + 32, lB2);
    ASYNC_CP16(brow1 + 32, lB3);
    arow0 += 64; arow1 += 64; brow0 += 64; brow1 += 64;
    __syncthreads();
    short8 av[2][4], bv[2][4];
#pragma unroll
    for (int t = 0; t < 2; t++)
#pragma unroll
      for (int kk = 0; kk < 4; kk++) {
        int idx = (kk >> 1) * 4096 + (kk & 1) * 16 + k8;
        av[t][kk] = *(const short8*)&As[idx + (wave_m * 64 + t * 32 + am) * 32];
        bv[t][kk] = *(const short8*)&Bs[idx + (wave_n * 64 + t * 32 + am) * 32];
      }
#pragma unroll
    for (int kk = 0; kk < 4; kk++)
#pragma unroll
      for (int ti = 0; ti < 2; ti++)
#pragma unroll
        for (int tj = 0; tj < 2; tj++)
          acc[ti][tj] = __builtin_amdgcn_mfma_f32_32x32x16_bf16(
              av[ti][kk], bv[tj][kk], acc[ti][tj], 0, 0, 0);
    __syncthreads();
  }

  // ---- epilogue: C/D 32x32 layout: col=lane&31, row=(reg&3)+8*(reg>>2)+4*(lane>>5) ----
  int hi = lane >> 5;
#pragma unroll
  for (int ti = 0; ti < 2; ti++) {
    int rbase = wave_m * 64 + ti * 32 + hi * 4;
    if (MODE == 1) {
#pragma unroll
      for (int tj = 0; tj < 2; tj++) {
        int col = n0 + wave_n * 64 + tj * 32 + am;
        float bv_ = bias[e * NDIM + col];
#pragma unroll
        for (int r = 0; r < 16; r++) {
          int m_l = rbase + (r & 3) + 8 * (r >> 2);
          float v = acc[ti][tj][r] + bv_;
          float gl = 0.5f * v * (1.0f + erff(v * 0.70710678118f));  // exact GELU
          hout[((size_t)e * K_CAP + m0 + m_l) * H_DIM + col] = (unsigned short)f2bf_u(gl);
        }
      }
    } else {
      int toks[16]; float wgts[16];
#pragma unroll
      for (int r = 0; r < 16; r++) {
        int m_l = rbase + (r & 3) + 8 * (r >> 2);
        toks[r] = sel[e * K_CAP + m0 + m_l];
        wgts[r] = wt[e * K_CAP + m0 + m_l];
      }
#pragma unroll
      for (int tj = 0; tj < 2; tj++) {
        int col = n0 + wave_n * 64 + tj * 32 + am;
        float bv_ = add_bias ? bias[e * NDIM + col] : 0.0f;
#pragma unroll
        for (int r = 0; r < 16; r++) {
          float v = (acc[ti][tj][r] + bv_) * wgts[r];
          atomicAdd(&results[(size_t)toks[r] * D_DIM + col], v);
        }
      }
    }
  }
}

// GEMM1: H = gelu(Xg @ W1 + b1). Linear grid (r2-proven scheduling).
__global__ __launch_bounds__(256, 2)
void moe_gemm1(const unsigned short* __restrict__ x_bf,
               const unsigned short* __restrict__ w1t,
               const float* __restrict__ b1,
               const int* __restrict__ sel,
               unsigned short* __restrict__ h) {
  gemm_core<1, D_DIM, H_DIM>(blockIdx.z, blockIdx.y * 128, blockIdx.x * 128,
                             0, D_DIM, true, x_bf, w1t, b1, sel, nullptr, h, nullptr);
}

// GEMM2: results += wt * (H @ W2 + b2). Expert-per-XCD + split-K=2.
__global__ __launch_bounds__(256, 2)
void moe_gemm2(const unsigned short* __restrict__ h,
               const unsigned short* __restrict__ w2t,
               const float* __restrict__ b2,
               const int* __restrict__ sel,
               const float* __restrict__ wt,
               float* __restrict__ results) {
  int e = blockIdx.x;
  int rest = blockIdx.y;
  int s = rest & 1;
  int nt = (rest >> 1) & 7;
  int mt = rest >> 4;
  gemm_core<2, H_DIM, D_DIM>(e, mt * 128, nt * 128, s * (H_DIM / 2), H_DIM / 2,
                             s == 0, h, w2t, b2, sel, wt, nullptr, results);
}

extern "C" void kernel_launch(void* const* d_in, const int* in_sizes, int n_in,
                              void* d_out, int out_size, void* d_ws, size_t ws_size,
                              hipStream_t stream) {
  const float* x  = (const float*)d_in[0];
  const float* rw = (const float*)d_in[1];
  const float* w1 = (const float*)d_in[2];
  const float* b1 = (const float*)d_in[3];
  const float* w2 = (const float*)d_in[4];
  const float* b2 = (const float*)d_in[5];

  float* out_res = (float*)d_out;                      // [8192][1024] fp32
  float* out_log = out_res + (size_t)T_TOK * D_DIM;    // [8192][8] fp32
  float* out_sel = out_log + (size_t)T_TOK * E_EXP;    // [8][1024] token ids as float

  char* ws = (char*)d_ws;
  float* probs_ws = (float*)ws;                                      // 256KB
  unsigned long long* keys_ws = (unsigned long long*)(ws + 262144);  // 512KB
  int* sel_ws = (int*)(ws + 786432);                                 // 32KB
  float* wt_ws = (float*)(ws + 819200);                              // 32KB
  unsigned short* x_bf = (unsigned short*)(ws + 1048576);            // 16MB
  unsigned short* h_ws = (unsigned short*)(ws + 17825792);           // 64MB
  unsigned short* t_buf = (unsigned short*)(ws + 84934656);          // 64MB (w1t, then w2t)

  zero_kernel<<<(T_TOK * D_DIM / 4 + 255) / 256, 256, 0, stream>>>(out_res, T_TOK * D_DIM / 4);

  router_kernel<<<T_TOK, 256, 0, stream>>>(x, rw, out_log, probs_ws, keys_ws, x_bf);

  topk_kernel<<<256, 256, 0, stream>>>(keys_ws, probs_ws, sel_ws, wt_ws, out_sel);

  // w1 [E][D][H] -> w1t [E][H][D] bf16
  transpose_kernel<D_DIM, H_DIM><<<dim3(H_DIM / 64, D_DIM / 64, E_EXP), 256, 0, stream>>>(
      w1, t_buf);

  moe_gemm1<<<dim3(H_DIM / 128, K_CAP / 128, E_EXP), 256, 0, stream>>>(
      x_bf, t_buf, b1, sel_ws, h_ws);

  // w2 [E][H][D] -> w2t [E][D][H] bf16 (reuse t_buf)
  transpose_kernel<H_DIM, D_DIM><<<dim3(D_DIM / 64, H_DIM / 64, E_EXP), 256, 0, stream>>>(
      w2, t_buf);

  moe_gemm2<<<dim3(E_EXP, (D_DIM / 128) * (K_CAP / 128) * 2), 256, 0, stream>>>(
      h_ws, t_buf, b2, sel_ws, wt_ws, out_res);
}